// Round 2
// baseline (105.395 us; speedup 1.0000x reference)
//
#include <hip/hip_runtime.h>
#include <hip/hip_bf16.h>
#include <stdint.h>

// Upsample2x(nearest) + Conv3x3(pad1) + bias via the parity trick:
//   out[b,co,2r+py,2s+px] = bias[co] +
//     sum_{ky,kx in {0,1}, ci} weff[py,px][co][ky,kx,ci] * xpad[b, r+py+ky, s+px+kx, ci]
// 4 parity GEMMs: M=512(co) x N=8192(b,r,s) x K=2048.
// R2: 8-phase-style deep pipeline: BM=256 x BN=256 x BK=32, 8 waves (2Mx4N),
// 4-deep LDS ring (4 x (16KB A + 16KB B) = 128 KB), counted vmcnt(8) gates
// (never 0 in main loop), setprio(1) around MFMA clusters, XCD-chunked bid map.

typedef __attribute__((ext_vector_type(8)))  __bf16 bf16x8;
typedef __attribute__((ext_vector_type(4)))  float  f32x4;
typedef __attribute__((ext_vector_type(4)))  int    int4v;

__device__ __forceinline__ void async16(const void* g, void* l) {
  __builtin_amdgcn_global_load_lds(
      (const __attribute__((address_space(1))) void*)g,
      (__attribute__((address_space(3))) void*)l,
      16, 0, 0);
}

// ---------------------------------------------------------------------------
__global__ void prep_weff(const float* __restrict__ w,
                          __hip_bfloat16* __restrict__ weff) {
  const int idx = blockIdx.x * 256 + threadIdx.x;   // co*512 + ci
  const int co = idx >> 9;
  const int ci = idx & 511;
  const float* wp = w + (size_t)idx * 9;            // [co][ci][3][3]
  float t[9];
#pragma unroll
  for (int i = 0; i < 9; ++i) t[i] = wp[i];
#pragma unroll
  for (int py = 0; py < 2; ++py) {
#pragma unroll
    for (int px = 0; px < 2; ++px) {
      const int p = py * 2 + px;
#pragma unroll
      for (int ky = 0; ky < 2; ++ky) {
        const int ulo = (ky == 0) ? 0 : (py == 0 ? 1 : 2);
        const int uhi = (ky == 0) ? (py == 0 ? 0 : 1) : 2;
#pragma unroll
        for (int kx = 0; kx < 2; ++kx) {
          const int vlo = (kx == 0) ? 0 : (px == 0 ? 1 : 2);
          const int vhi = (kx == 0) ? (px == 0 ? 0 : 1) : 2;
          float s = 0.f;
          for (int u = ulo; u <= uhi; ++u)
            for (int v = vlo; v <= vhi; ++v)
              s += t[u * 3 + v];
          const int kk = ky * 2 + kx;
          weff[(((size_t)p * 512 + co) * 4 + kk) * 512 + ci] = __float2bfloat16(s);
        }
      }
    }
  }
}

// ---------------------------------------------------------------------------
__global__ void prep_xpad(const float* __restrict__ x,
                          __hip_bfloat16* __restrict__ xpad) {
  const int blk = blockIdx.x;          // 8b * 32r * 8cib = 2048
  const int cib = blk & 7;
  const int r   = (blk >> 3) & 31;
  const int b   = blk >> 8;
  const int tid = threadIdx.x;
  __shared__ __align__(16) __hip_bfloat16 ldsT[32][80];
  const int ci_l = tid >> 2;
  const int wq   = tid & 3;
  const float* xp = x + (((size_t)(b * 512 + cib * 64 + ci_l) * 32 + r) * 32) + wq * 8;
  float4 v0 = *(const float4*)(xp);
  float4 v1 = *(const float4*)(xp + 4);
  const int wb = wq * 8;
  ldsT[wb + 0][ci_l] = __float2bfloat16(v0.x);
  ldsT[wb + 1][ci_l] = __float2bfloat16(v0.y);
  ldsT[wb + 2][ci_l] = __float2bfloat16(v0.z);
  ldsT[wb + 3][ci_l] = __float2bfloat16(v0.w);
  ldsT[wb + 4][ci_l] = __float2bfloat16(v1.x);
  ldsT[wb + 5][ci_l] = __float2bfloat16(v1.y);
  ldsT[wb + 6][ci_l] = __float2bfloat16(v1.z);
  ldsT[wb + 7][ci_l] = __float2bfloat16(v1.w);
  __syncthreads();
  const int w_o = tid >> 3;
  const int ch  = tid & 7;
  char* dst = (char*)xpad +
      ((((size_t)(b * 34 + (r + 1)) * 34) + (w_o + 1)) * 512 + cib * 64 + ch * 8) * 2;
  *(int4v*)dst = *(const int4v*)&ldsT[w_o][ch * 8];
}

// ---------------------------------------------------------------------------
// Main GEMM. Per K-tile (BK=32): 2 phases x 16 MFMA. LDS rows are 64 B (16
// banks x 4 slots of 16B); XOR swizzle s_phys = s_log ^ ((row>>1)&3), applied
// on the GLOBAL source (staging) and on the ds_read address (rule #21).
#define MM(a, b, c) __builtin_amdgcn_mfma_f32_16x16x32_bf16((a), (b), (c), 0, 0, 0)

#define STAGE_A(t3) do { const int _bf = (t3) & 3; const size_t _ka = (size_t)(t3) * 32; \
    async16(gA0 + _ka, lds + _bf * 16384 + dstA);                                        \
    async16(gA1 + _ka, lds + _bf * 16384 + 8192 + dstA); } while (0)

#define STAGE_B(t3) do { const int _bf = (t3) & 3;                                       \
    const int _kb = (((t3) >> 5) * 34 + (((t3) >> 4) & 1)) * 512 + ((t3) & 15) * 32;     \
    async16(gB0 + _kb, lds + _bf * 16384 + dstB);                                        \
    async16(gB1 + _kb, lds + _bf * 16384 + 8192 + dstB); } while (0)

#define MFMA16(mb) do {                                                            \
    acc[mb+0][0]=MM(a0,b0,acc[mb+0][0]); acc[mb+0][1]=MM(a0,b1,acc[mb+0][1]);      \
    acc[mb+0][2]=MM(a0,b2,acc[mb+0][2]); acc[mb+0][3]=MM(a0,b3,acc[mb+0][3]);      \
    acc[mb+1][0]=MM(a1,b0,acc[mb+1][0]); acc[mb+1][1]=MM(a1,b1,acc[mb+1][1]);      \
    acc[mb+1][2]=MM(a1,b2,acc[mb+1][2]); acc[mb+1][3]=MM(a1,b3,acc[mb+1][3]);      \
    acc[mb+2][0]=MM(a2,b0,acc[mb+2][0]); acc[mb+2][1]=MM(a2,b1,acc[mb+2][1]);      \
    acc[mb+2][2]=MM(a2,b2,acc[mb+2][2]); acc[mb+2][3]=MM(a2,b3,acc[mb+2][3]);      \
    acc[mb+3][0]=MM(a3,b0,acc[mb+3][0]); acc[mb+3][1]=MM(a3,b1,acc[mb+3][1]);      \
    acc[mb+3][2]=MM(a3,b2,acc[mb+3][2]); acc[mb+3][3]=MM(a3,b3,acc[mb+3][3]); } while (0)

#define TILE(t, DOSTAGE, GATE) do {                                                \
    const int _buf = (t) & 3;                                                      \
    const char* LA = lds + _buf * 16384 + laneA;                                   \
    const char* LB = lds + _buf * 16384 + laneB;                                   \
    bf16x8 a0, a1, a2, a3, b0, b1, b2, b3;                                         \
    a0 = *(const bf16x8*)(LA);        a1 = *(const bf16x8*)(LA + 1024);            \
    a2 = *(const bf16x8*)(LA + 2048); a3 = *(const bf16x8*)(LA + 3072);            \
    b0 = *(const bf16x8*)(LB);        b1 = *(const bf16x8*)(LB + 1024);            \
    b2 = *(const bf16x8*)(LB + 2048); b3 = *(const bf16x8*)(LB + 3072);            \
    if (DOSTAGE) STAGE_A((t) + 3);                                                 \
    asm volatile("s_barrier" ::: "memory");                                        \
    __builtin_amdgcn_s_setprio(1);                                                 \
    MFMA16(0);                                                                     \
    __builtin_amdgcn_s_setprio(0);                                                 \
    asm volatile("s_barrier" ::: "memory");                                        \
    a0 = *(const bf16x8*)(LA + 4096); a1 = *(const bf16x8*)(LA + 5120);            \
    a2 = *(const bf16x8*)(LA + 6144); a3 = *(const bf16x8*)(LA + 7168);            \
    if (DOSTAGE) STAGE_B((t) + 3);                                                 \
    asm volatile("s_barrier" ::: "memory");                                        \
    __builtin_amdgcn_s_setprio(1);                                                 \
    MFMA16(4);                                                                     \
    __builtin_amdgcn_s_setprio(0);                                                 \
    asm volatile("s_waitcnt vmcnt(" GATE ")\n\ts_barrier" ::: "memory");           \
  } while (0)

__global__ __launch_bounds__(512, 2) void upconv_gemm(
    const __hip_bfloat16* __restrict__ xpad,   // [8][34][34][512]
    const __hip_bfloat16* __restrict__ weff,   // [4][512][2048]
    const float* __restrict__ bias,
    float* __restrict__ out) {                 // [8][512][64][64]
  extern __shared__ __align__(16) char lds[]; // 131072 B: A ring @0, B ring @65536

  // XCD-chunked map: group g = bid%8 -> {1 parity, both m-tiles, 16 n-tiles}
  const int bid = blockIdx.x;
  const int g = bid & 7, i = bid >> 3;
  const int p  = g >> 1;
  const int py = p >> 1, px = p & 1;
  const int mt = i & 1;
  const int nt = (g & 1) * 16 + (i >> 1);
  const int co0 = mt << 8;
  const int n0  = nt << 8;
  const int b   = n0 >> 10;
  const int rb  = (n0 & 1023) >> 5;   // 0,8,16,24

  const int tid  = threadIdx.x;
  const int lane = tid & 63;
  const int wv   = tid >> 6;           // 0..7
  const int wr   = wv >> 2;            // 0..1 : M half (128 rows)
  const int wc   = wv & 3;             // 0..3 : N quarter (64 cols)

  // ---- staging (global -> LDS ring) per-thread addressing
  const int srow = tid >> 2;           // 0..127
  const int sp   = tid & 3;            // physical 16B slot
  const int slog = sp ^ ((srow >> 1) & 3);   // logical k-slot this thread fetches

  const __hip_bfloat16* wp  = weff + ((size_t)p << 20);              // p*512*2048
  const __hip_bfloat16* gA0 = wp + (size_t)(co0 + srow) * 2048 + slog * 8;
  const __hip_bfloat16* gA1 = gA0 + (size_t)128 * 2048;
  const int nl1 = 128 + srow;
  const __hip_bfloat16* gB0 = xpad +
      ((size_t)(b * 34 + rb + (srow >> 5) + py) * 34 + ((srow & 31) + px)) * 512 + slog * 8;
  const __hip_bfloat16* gB1 = xpad +
      ((size_t)(b * 34 + rb + (nl1 >> 5) + py) * 34 + ((nl1 & 31) + px)) * 512 + slog * 8;

  const int dstA = wv * 1024;          // wave-uniform LDS staging bases
  const int dstB = 65536 + wv * 1024;

  // ---- fragment ds_read addressing (swizzled)
  const int fsp   = (lane >> 4) ^ ((lane >> 1) & 3);
  const int laneA = (wr * 128 + (lane & 15)) * 64 + fsp * 16;
  const int laneB = 65536 + (wc * 64 + (lane & 15)) * 64 + fsp * 16;

  f32x4 acc[8][4] = {};

  // ---- prologue: stage K-tiles 0,1,2 (12 loads in flight)
  STAGE_A(0); STAGE_B(0);
  STAGE_A(1); STAGE_B(1);
  STAGE_A(2); STAGE_B(2);
  asm volatile("s_waitcnt vmcnt(8)\n\ts_barrier" ::: "memory"); // tile 0 landed

  // ---- main loop: 64 K-tiles, prefetch distance 3, gate vmcnt(8)
#pragma unroll 1
  for (int t = 0; t < 61; ++t) TILE(t, true, "8");
  TILE(61, false, "4");
  TILE(62, false, "0");
  TILE(63, false, "0");

  // ---- epilogue: D layout row=(lane>>4)*4+j, col=lane&15 (m89)
#pragma unroll
  for (int m = 0; m < 8; ++m) {
    const int coB = co0 + wr * 128 + m * 16 + ((lane >> 4) << 2);
    float bv[4];
#pragma unroll
    for (int j = 0; j < 4; ++j) bv[j] = bias[coB + j];
#pragma unroll
    for (int nn = 0; nn < 4; ++nn) {
      const int nl = wc * 64 + nn * 16 + (lane & 15);
      const int rr = rb + (nl >> 5);
      const int ss = nl & 31;
      const int oh = rr * 2 + py;
      const int ow = ss * 2 + px;
      float* op = out + (((size_t)(b * 512 + coB) << 6) + oh) * 64 + ow;
#pragma unroll
      for (int j = 0; j < 4; ++j)
        op[(size_t)j * 4096] = acc[m][nn][j] + bv[j];
    }
  }
}

// ---------------------------------------------------------------------------
extern "C" void kernel_launch(void* const* d_in, const int* in_sizes, int n_in,
                              void* d_out, int out_size, void* d_ws, size_t ws_size,
                              hipStream_t stream) {
  (void)in_sizes; (void)n_in; (void)out_size; (void)ws_size;
  const float* x  = (const float*)d_in[0];   // [8][512][32][32]
  const float* w  = (const float*)d_in[1];   // [512][512][3][3]
  const float* bs = (const float*)d_in[2];   // [512]
  float* out = (float*)d_out;                // [8][512][64][64]
  char* ws = (char*)d_ws;
  __hip_bfloat16* xpad = (__hip_bfloat16*)ws;                 // 9,467,904 B
  __hip_bfloat16* weff = (__hip_bfloat16*)(ws + (10u << 20)); // 8,388,608 B
  hipMemsetAsync(xpad, 0, (size_t)8 * 34 * 34 * 512 * 2, stream);
  prep_weff<<<dim3(1024), dim3(256), 0, stream>>>(w, weff);
  prep_xpad<<<dim3(2048), dim3(256), 0, stream>>>(x, xpad);
  upconv_gemm<<<dim3(256), dim3(512), 131072, stream>>>(xpad, weff, bs, out);
}

// Round 3
// 101.925 us; speedup vs baseline: 1.0340x; 1.0340x over previous
//
#include <hip/hip_runtime.h>
#include <hip/hip_bf16.h>
#include <stdint.h>

// Upsample2x(nearest) + Conv3x3(pad1) + bias via the parity trick:
//   out[b,co,2r+py,2s+px] = bias[co] +
//     sum_{ky,kx in {0,1}, ci} weff[py,px][co][ky,kx,ci] * xpad[b, r+py+ky, s+px+kx, ci]
// 4 parity GEMMs: M=512(co) x N=8192(b,r,s) x K=2048.
// R3: BM=256 x BN=256 x BK=32, 8 waves (2Mx4N), 4-deep LDS ring, fragment
// ds_reads pipelined ONE PHASE AHEAD (latency hidden under MFMA), one
// vmcnt(6)+barrier gate per K-tile, setprio(1) around MFMA clusters.

typedef __attribute__((ext_vector_type(8)))  __bf16 bf16x8;
typedef __attribute__((ext_vector_type(4)))  float  f32x4;
typedef __attribute__((ext_vector_type(4)))  int    int4v;

__device__ __forceinline__ void async16(const void* g, void* l) {
  __builtin_amdgcn_global_load_lds(
      (const __attribute__((address_space(1))) void*)g,
      (__attribute__((address_space(3))) void*)l,
      16, 0, 0);
}

// ---------------------------------------------------------------------------
__global__ void prep_weff(const float* __restrict__ w,
                          __hip_bfloat16* __restrict__ weff) {
  const int idx = blockIdx.x * 256 + threadIdx.x;   // co*512 + ci
  const int co = idx >> 9;
  const int ci = idx & 511;
  const float* wp = w + (size_t)idx * 9;            // [co][ci][3][3]
  float t[9];
#pragma unroll
  for (int i = 0; i < 9; ++i) t[i] = wp[i];
#pragma unroll
  for (int py = 0; py < 2; ++py) {
#pragma unroll
    for (int px = 0; px < 2; ++px) {
      const int p = py * 2 + px;
#pragma unroll
      for (int ky = 0; ky < 2; ++ky) {
        const int ulo = (ky == 0) ? 0 : (py == 0 ? 1 : 2);
        const int uhi = (ky == 0) ? (py == 0 ? 0 : 1) : 2;
#pragma unroll
        for (int kx = 0; kx < 2; ++kx) {
          const int vlo = (kx == 0) ? 0 : (px == 0 ? 1 : 2);
          const int vhi = (kx == 0) ? (px == 0 ? 0 : 1) : 2;
          float s = 0.f;
          for (int u = ulo; u <= uhi; ++u)
            for (int v = vlo; v <= vhi; ++v)
              s += t[u * 3 + v];
          const int kk = ky * 2 + kx;
          weff[(((size_t)p * 512 + co) * 4 + kk) * 512 + ci] = __float2bfloat16(s);
        }
      }
    }
  }
}

// ---------------------------------------------------------------------------
__global__ void prep_xpad(const float* __restrict__ x,
                          __hip_bfloat16* __restrict__ xpad) {
  const int blk = blockIdx.x;          // 8b * 32r * 8cib = 2048
  const int cib = blk & 7;
  const int r   = (blk >> 3) & 31;
  const int b   = blk >> 8;
  const int tid = threadIdx.x;
  __shared__ __align__(16) __hip_bfloat16 ldsT[32][80];
  const int ci_l = tid >> 2;
  const int wq   = tid & 3;
  const float* xp = x + (((size_t)(b * 512 + cib * 64 + ci_l) * 32 + r) * 32) + wq * 8;
  float4 v0 = *(const float4*)(xp);
  float4 v1 = *(const float4*)(xp + 4);
  const int wb = wq * 8;
  ldsT[wb + 0][ci_l] = __float2bfloat16(v0.x);
  ldsT[wb + 1][ci_l] = __float2bfloat16(v0.y);
  ldsT[wb + 2][ci_l] = __float2bfloat16(v0.z);
  ldsT[wb + 3][ci_l] = __float2bfloat16(v0.w);
  ldsT[wb + 4][ci_l] = __float2bfloat16(v1.x);
  ldsT[wb + 5][ci_l] = __float2bfloat16(v1.y);
  ldsT[wb + 6][ci_l] = __float2bfloat16(v1.z);
  ldsT[wb + 7][ci_l] = __float2bfloat16(v1.w);
  __syncthreads();
  const int w_o = tid >> 3;
  const int ch  = tid & 7;
  char* dst = (char*)xpad +
      ((((size_t)(b * 34 + (r + 1)) * 34) + (w_o + 1)) * 512 + cib * 64 + ch * 8) * 2;
  *(int4v*)dst = *(const int4v*)&ldsT[w_o][ch * 8];
}

// ---------------------------------------------------------------------------
// LDS rows are 64 B (4 slots of 16 B); XOR swizzle s_phys = s_log ^ ((row>>1)&3),
// applied on the GLOBAL source (staging) and on the ds_read address (rule #21).
// Ring: 4 buffers x (A 16KB @ buf*16384, B 16KB @ 65536 + buf*16384).
#define MM(a, b, c) __builtin_amdgcn_mfma_f32_16x16x32_bf16((a), (b), (c), 0, 0, 0)

#define STAGE_A(t3) do { const int _bf = (t3) & 3; const size_t _ka = (size_t)(t3) * 32; \
    async16(gA0 + _ka, lds + _bf * 16384 + dstA);                                        \
    async16(gA1 + _ka, lds + _bf * 16384 + 8192 + dstA); } while (0)

#define STAGE_B(t3) do { const int _bf = (t3) & 3;                                       \
    const int _kb = (((t3) >> 5) * 34 + (((t3) >> 4) & 1)) * 512 + ((t3) & 15) * 32;     \
    async16(gB0 + _kb, lds + _bf * 16384 + dstB);                                        \
    async16(gB1 + _kb, lds + _bf * 16384 + 8192 + dstB); } while (0)

#define RD_A03(D, t) do { const char* _p = lds + ((t) & 3) * 16384 + laneA;              \
    (D)[0] = *(const bf16x8*)(_p);        (D)[1] = *(const bf16x8*)(_p + 1024);          \
    (D)[2] = *(const bf16x8*)(_p + 2048); (D)[3] = *(const bf16x8*)(_p + 3072); } while (0)

#define RD_A47(D, t) do { const char* _p = lds + ((t) & 3) * 16384 + laneA + 4096;       \
    (D)[0] = *(const bf16x8*)(_p);        (D)[1] = *(const bf16x8*)(_p + 1024);          \
    (D)[2] = *(const bf16x8*)(_p + 2048); (D)[3] = *(const bf16x8*)(_p + 3072); } while (0)

#define RD_B(D, t) do { const char* _p = lds + ((t) & 3) * 16384 + laneB;                \
    (D)[0] = *(const bf16x8*)(_p);        (D)[1] = *(const bf16x8*)(_p + 1024);          \
    (D)[2] = *(const bf16x8*)(_p + 2048); (D)[3] = *(const bf16x8*)(_p + 3072); } while (0)

#define MFMA16(mb, A, B) do {                                                            \
    _Pragma("unroll")                                                                    \
    for (int _i = 0; _i < 4; ++_i)                                                       \
      _Pragma("unroll")                                                                  \
      for (int _j = 0; _j < 4; ++_j)                                                     \
        acc[(mb) + _i][_j] = MM((A)[_i], (B)[_j], acc[(mb) + _i][_j]);                   \
  } while (0)

// Per K-tile: PH1 { read A47[t] | stage A(t+3) | MFMA m0-3 } gate{vmcnt,barrier}
//             PH2 { read A03/B[t+1] | stage B(t+3) | MFMA m4-7 }
#define TILE_BODY(t, AC, BC, AN, BN, DOSTAGE, RDNEXT, GATE) do {                         \
    RD_A47(a47, (t));                                                                    \
    if (DOSTAGE) STAGE_A((t) + 3);                                                       \
    __builtin_amdgcn_s_setprio(1);                                                       \
    MFMA16(0, AC, BC);                                                                   \
    __builtin_amdgcn_s_setprio(0);                                                       \
    asm volatile("s_waitcnt vmcnt(" GATE ")\n\ts_barrier" ::: "memory");                 \
    if (RDNEXT) { RD_A03(AN, (t) + 1); RD_B(BN, (t) + 1); }                              \
    if (DOSTAGE) STAGE_B((t) + 3);                                                       \
    __builtin_amdgcn_s_setprio(1);                                                       \
    MFMA16(4, a47, BC);                                                                  \
    __builtin_amdgcn_s_setprio(0);                                                       \
  } while (0)

__global__ __launch_bounds__(512, 2) void upconv_gemm(
    const __hip_bfloat16* __restrict__ xpad,   // [8][34][34][512]
    const __hip_bfloat16* __restrict__ weff,   // [4][512][2048]
    const float* __restrict__ bias,
    float* __restrict__ out) {                 // [8][512][64][64]
  extern __shared__ __align__(16) char lds[]; // 131072 B

  // XCD-chunked map: group g = bid%8 -> {1 parity, both m-tiles, 16 n-tiles}
  const int bid = blockIdx.x;
  const int g = bid & 7, i = bid >> 3;
  const int p  = g >> 1;
  const int py = p >> 1, px = p & 1;
  const int mt = i & 1;
  const int nt = (g & 1) * 16 + (i >> 1);
  const int co0 = mt << 8;
  const int n0  = nt << 8;
  const int b   = n0 >> 10;
  const int rb  = (n0 & 1023) >> 5;   // 0,8,16,24

  const int tid  = threadIdx.x;
  const int lane = tid & 63;
  const int wv   = tid >> 6;           // 0..7
  const int wr   = wv >> 2;            // 0..1 : M half (128 rows)
  const int wc   = wv & 3;             // 0..3 : N quarter (64 cols)

  // ---- staging (global -> LDS ring) per-thread addressing
  const int srow = tid >> 2;           // 0..127
  const int sp   = tid & 3;            // physical 16B slot
  const int slog = sp ^ ((srow >> 1) & 3);   // logical k-slot this thread fetches

  const __hip_bfloat16* wp  = weff + ((size_t)p << 20);              // p*512*2048
  const __hip_bfloat16* gA0 = wp + (size_t)(co0 + srow) * 2048 + slog * 8;
  const __hip_bfloat16* gA1 = gA0 + (size_t)128 * 2048;
  const int nl1 = 128 + srow;
  const __hip_bfloat16* gB0 = xpad +
      ((size_t)(b * 34 + rb + (srow >> 5) + py) * 34 + ((srow & 31) + px)) * 512 + slog * 8;
  const __hip_bfloat16* gB1 = xpad +
      ((size_t)(b * 34 + rb + (nl1 >> 5) + py) * 34 + ((nl1 & 31) + px)) * 512 + slog * 8;

  const int dstA = wv * 1024;          // wave-uniform LDS staging bases
  const int dstB = 65536 + wv * 1024;

  // ---- fragment ds_read addressing (swizzled)
  const int fsp   = (lane >> 4) ^ ((lane >> 1) & 3);
  const int laneA = (wr * 128 + (lane & 15)) * 64 + fsp * 16;
  const int laneB = 65536 + (wc * 64 + (lane & 15)) * 64 + fsp * 16;

  f32x4 acc[8][4] = {};
  bf16x8 a0[4], a1[4], b0v[4], b1v[4], a47[4];

  // ---- prologue: stage K-tiles 0,1,2; wait tile 0; pre-read tile 0 frags
  STAGE_A(0); STAGE_B(0);
  STAGE_A(1); STAGE_B(1);
  STAGE_A(2); STAGE_B(2);
  asm volatile("s_waitcnt vmcnt(8)\n\ts_barrier" ::: "memory"); // tile 0 landed
  RD_A03(a0, 0);
  RD_B(b0v, 0);

  // ---- main loop: 64 K-tiles, prefetch distance 3, steady gate vmcnt(6)
#pragma unroll 1
  for (int t = 0; t < 60; t += 2) {
    TILE_BODY(t,     a0, b0v, a1, b1v, true, true, "6");
    TILE_BODY(t + 1, a1, b1v, a0, b0v, true, true, "6");
  }
  TILE_BODY(60, a0, b0v, a1, b1v, true,  true,  "6");
  TILE_BODY(61, a1, b1v, a0, b0v, false, true,  "4");
  TILE_BODY(62, a0, b0v, a1, b1v, false, true,  "0");
  TILE_BODY(63, a1, b1v, a0, b0v, false, false, "0");

  // ---- epilogue: D layout row=(lane>>4)*4+j, col=lane&15 (m89)
#pragma unroll
  for (int m = 0; m < 8; ++m) {
    const int coB = co0 + wr * 128 + m * 16 + ((lane >> 4) << 2);
    float bv[4];
#pragma unroll
    for (int j = 0; j < 4; ++j) bv[j] = bias[coB + j];
#pragma unroll
    for (int nn = 0; nn < 4; ++nn) {
      const int nl = wc * 64 + nn * 16 + (lane & 15);
      const int rr = rb + (nl >> 5);
      const int ss = nl & 31;
      const int oh = rr * 2 + py;
      const int ow = ss * 2 + px;
      float* op = out + (((size_t)(b * 512 + coB) << 6) + oh) * 64 + ow;
#pragma unroll
      for (int j = 0; j < 4; ++j)
        op[(size_t)j * 4096] = acc[m][nn][j] + bv[j];
    }
  }
}

// ---------------------------------------------------------------------------
extern "C" void kernel_launch(void* const* d_in, const int* in_sizes, int n_in,
                              void* d_out, int out_size, void* d_ws, size_t ws_size,
                              hipStream_t stream) {
  (void)in_sizes; (void)n_in; (void)out_size; (void)ws_size;
  const float* x  = (const float*)d_in[0];   // [8][512][32][32]
  const float* w  = (const float*)d_in[1];   // [512][512][3][3]
  const float* bs = (const float*)d_in[2];   // [512]
  float* out = (float*)d_out;                // [8][512][64][64]
  char* ws = (char*)d_ws;
  __hip_bfloat16* xpad = (__hip_bfloat16*)ws;                 // 9,467,904 B
  __hip_bfloat16* weff = (__hip_bfloat16*)(ws + (10u << 20)); // 8,388,608 B
  hipMemsetAsync(xpad, 0, (size_t)8 * 34 * 34 * 512 * 2, stream);
  prep_weff<<<dim3(1024), dim3(256), 0, stream>>>(w, weff);
  prep_xpad<<<dim3(2048), dim3(256), 0, stream>>>(x, xpad);
  upconv_gemm<<<dim3(256), dim3(512), 131072, stream>>>(xpad, weff, bs, out);
}

// Round 4
// 91.319 us; speedup vs baseline: 1.1541x; 1.1162x over previous
//
#include <hip/hip_runtime.h>
#include <hip/hip_bf16.h>
#include <stdint.h>

// Upsample2x(nearest) + Conv3x3(pad1) + bias via the parity trick:
//   out[b,co,2r+py,2s+px] = bias[co] +
//     sum_{ky,kx in {0,1}, ci} weff[py,px][co][ky,kx,ci] * xpad[b, r+py+ky, s+px+kx, ci]
// 4 parity GEMMs: M=512(co) x N=8192(b,r,s) x K=2048.
// R4: m201-style 8-phase schedule. BM=BN=256, BK=64, 8 waves (2Mx4N),
// 2-slot double-buffer (4 x 32KB = 128KB LDS), per-phase {ds_read frags |
// stage 1 half | barrier | setprio MFMA x16 | barrier}, counted vmcnt(2)
// gates at ph3/ph7 only. XOR slot swizzle (8 slots/128B row) on both the
// global staging source and the ds_read address (rule #21). px-twin XCD map.

typedef __attribute__((ext_vector_type(8)))  __bf16 bf16x8;
typedef __attribute__((ext_vector_type(4)))  float  f32x4;
typedef __attribute__((ext_vector_type(4)))  int    int4v;

__device__ __forceinline__ void async16(const void* g, void* l) {
  __builtin_amdgcn_global_load_lds(
      (const __attribute__((address_space(1))) void*)g,
      (__attribute__((address_space(3))) void*)l,
      16, 0, 0);
}

// ---------------------------------------------------------------------------
__global__ void prep_weff(const float* __restrict__ w,
                          __hip_bfloat16* __restrict__ weff) {
  const int idx = blockIdx.x * 256 + threadIdx.x;   // co*512 + ci
  const int co = idx >> 9;
  const int ci = idx & 511;
  const float* wp = w + (size_t)idx * 9;            // [co][ci][3][3]
  float t[9];
#pragma unroll
  for (int i = 0; i < 9; ++i) t[i] = wp[i];
#pragma unroll
  for (int py = 0; py < 2; ++py) {
#pragma unroll
    for (int px = 0; px < 2; ++px) {
      const int p = py * 2 + px;
#pragma unroll
      for (int ky = 0; ky < 2; ++ky) {
        const int ulo = (ky == 0) ? 0 : (py == 0 ? 1 : 2);
        const int uhi = (ky == 0) ? (py == 0 ? 0 : 1) : 2;
#pragma unroll
        for (int kx = 0; kx < 2; ++kx) {
          const int vlo = (kx == 0) ? 0 : (px == 0 ? 1 : 2);
          const int vhi = (kx == 0) ? (px == 0 ? 0 : 1) : 2;
          float s = 0.f;
          for (int u = ulo; u <= uhi; ++u)
            for (int v = vlo; v <= vhi; ++v)
              s += t[u * 3 + v];
          const int kk = ky * 2 + kx;
          weff[(((size_t)p * 512 + co) * 4 + kk) * 512 + ci] = __float2bfloat16(s);
        }
      }
    }
  }
}

// ---------------------------------------------------------------------------
__global__ void prep_xpad(const float* __restrict__ x,
                          __hip_bfloat16* __restrict__ xpad) {
  const int blk = blockIdx.x;          // 8b * 32r * 8cib = 2048
  const int cib = blk & 7;
  const int r   = (blk >> 3) & 31;
  const int b   = blk >> 8;
  const int tid = threadIdx.x;
  __shared__ __align__(16) __hip_bfloat16 ldsT[32][80];
  const int ci_l = tid >> 2;
  const int wq   = tid & 3;
  const float* xp = x + (((size_t)(b * 512 + cib * 64 + ci_l) * 32 + r) * 32) + wq * 8;
  float4 v0 = *(const float4*)(xp);
  float4 v1 = *(const float4*)(xp + 4);
  const int wb = wq * 8;
  ldsT[wb + 0][ci_l] = __float2bfloat16(v0.x);
  ldsT[wb + 1][ci_l] = __float2bfloat16(v0.y);
  ldsT[wb + 2][ci_l] = __float2bfloat16(v0.z);
  ldsT[wb + 3][ci_l] = __float2bfloat16(v0.w);
  ldsT[wb + 4][ci_l] = __float2bfloat16(v1.x);
  ldsT[wb + 5][ci_l] = __float2bfloat16(v1.y);
  ldsT[wb + 6][ci_l] = __float2bfloat16(v1.z);
  ldsT[wb + 7][ci_l] = __float2bfloat16(v1.w);
  __syncthreads();
  const int w_o = tid >> 3;
  const int ch  = tid & 7;
  char* dst = (char*)xpad +
      ((((size_t)(b * 34 + (r + 1)) * 34) + (w_o + 1)) * 512 + cib * 64 + ch * 8) * 2;
  *(int4v*)dst = *(const int4v*)&ldsT[w_o][ch * 8];
}

// ---------------------------------------------------------------------------
// LDS: A slot d @ d*32768 (half h @ +h*16384), B @ 65536 + d*32768 + h*16384.
// Half layout: [128 rows][8 slots x 16B], phys slot = logical ^ (row&7).
#define MM(a, b, c) __builtin_amdgcn_mfma_f32_16x16x32_bf16((a), (b), (c), 0, 0, 0)
#define BAR() __builtin_amdgcn_s_barrier()
#define SCB() __builtin_amdgcn_sched_barrier(0)
#define PRIO(x) __builtin_amdgcn_s_setprio(x)
#define GATE(N) asm volatile("s_waitcnt vmcnt(" N ")" ::: "memory")

#define ST_A(T, h, d) do {                                                     \
    char* _l = lds + (d) * 32768 + (h) * 16384 + dA;                           \
    const __hip_bfloat16* _g = ((h) ? pA1 : pA0) + (size_t)(T) * 64;           \
    async16(_g, _l); async16(_g + 131072, _l + 8192); } while (0)

#define OFFB(T) (((((T) >> 4) * 34) + (((T) >> 3) & 1)) * 512 + ((T) & 7) * 64)
#define ST_B(T, h, d) do {                                                     \
    char* _l = lds + 65536 + (d) * 32768 + (h) * 16384 + dA;                   \
    const int _o = OFFB(T);                                                    \
    async16(((h) ? pB10 : pB00) + _o, _l);                                     \
    async16(((h) ? pB11 : pB01) + _o, _l + 8192); } while (0)

#define RD_A(D, S, mb) do {                                                    \
    _Pragma("unroll") for (int _m = 0; _m < 4; ++_m) {                         \
      (D)[_m * 2]     = *(const bf16x8*)((S) + ((mb) + _m) * 2048 + aoff0);    \
      (D)[_m * 2 + 1] = *(const bf16x8*)((S) + ((mb) + _m) * 2048 + aoff1); }  \
  } while (0)

#define RD_B(D, S, nb) do {                                                    \
    _Pragma("unroll") for (int _n = 0; _n < 2; ++_n) {                         \
      (D)[_n * 2]     = *(const bf16x8*)((S) + ((nb) + _n) * 2048 + aoff0);    \
      (D)[_n * 2 + 1] = *(const bf16x8*)((S) + ((nb) + _n) * 2048 + aoff1); }  \
  } while (0)

#define MFMAQ(mb, nb, A, B) do {                                               \
    _Pragma("unroll") for (int _m = 0; _m < 4; ++_m)                           \
      _Pragma("unroll") for (int _n = 0; _n < 2; ++_n) {                       \
        acc[(mb)+_m][(nb)+_n] = MM((A)[_m*2],   (B)[_n*2],   acc[(mb)+_m][(nb)+_n]); \
        acc[(mb)+_m][(nb)+_n] = MM((A)[_m*2+1], (B)[_n*2+1], acc[(mb)+_m][(nb)+_n]); } \
  } while (0)

// One iteration = 2 K-tiles (slot0 = T, slot1 = T+1), 8 phases.
// Stage windows: ph0-2 finish tile T+1 (slot1); ph3-6 tile T+2 (slot0);
// ph7 starts tile T+3 (slot1). Gates vmcnt(2) at ph3 (tile T+1 complete)
// and ph7 (tile T+2 complete).
#define ITER(T, SE, SM, S7, G3, G7) do {                                       \
  /*ph0*/ RD_A(A0, aS0, 0); RD_B(Bf, bS0, 0); if (SE) ST_A((T)+1, 1, 1);       \
    SCB(); BAR(); SCB(); PRIO(1); MFMAQ(0, 0, A0, Bf); PRIO(0); SCB(); BAR();  \
  /*ph1*/ RD_A(A1, aS0, 4); if (SE) ST_B((T)+1, 0, 1);                         \
    SCB(); BAR(); SCB(); PRIO(1); MFMAQ(4, 0, A1, Bf); PRIO(0); SCB(); BAR();  \
  /*ph2*/ RD_B(Bf, bS0, 2); if (SE) ST_B((T)+1, 1, 1);                         \
    SCB(); BAR(); SCB(); PRIO(1); MFMAQ(4, 2, A1, Bf); PRIO(0); SCB(); BAR();  \
  /*ph3*/ if (SM) ST_A((T)+2, 0, 0);                                           \
    SCB(); BAR(); SCB(); PRIO(1); MFMAQ(0, 2, A0, Bf); PRIO(0); SCB();         \
    GATE(G3); BAR();                                                           \
  /*ph4*/ RD_A(A0, aS1, 0); RD_B(Bf, bS1, 0); if (SM) ST_A((T)+2, 1, 0);       \
    SCB(); BAR(); SCB(); PRIO(1); MFMAQ(0, 0, A0, Bf); PRIO(0); SCB(); BAR();  \
  /*ph5*/ RD_A(A1, aS1, 4); if (SM) ST_B((T)+2, 0, 0);                         \
    SCB(); BAR(); SCB(); PRIO(1); MFMAQ(4, 0, A1, Bf); PRIO(0); SCB(); BAR();  \
  /*ph6*/ RD_B(Bf, bS1, 2); if (SM) ST_B((T)+2, 1, 0);                         \
    SCB(); BAR(); SCB(); PRIO(1); MFMAQ(4, 2, A1, Bf); PRIO(0); SCB(); BAR();  \
  /*ph7*/ if (S7) ST_A((T)+3, 0, 1);                                           \
    SCB(); BAR(); SCB(); PRIO(1); MFMAQ(0, 2, A0, Bf); PRIO(0); SCB();         \
    GATE(G7); BAR();                                                           \
} while (0)

__global__ __launch_bounds__(512, 2) void upconv_gemm(
    const __hip_bfloat16* __restrict__ xpad,   // [8][34][34][512]
    const __hip_bfloat16* __restrict__ weff,   // [4][512][2048]
    const float* __restrict__ bias,
    float* __restrict__ out) {                 // [8][512][64][64]
  extern __shared__ __align__(16) char lds[]; // 131072 B

  // px-twin XCD map: g = bid&7 -> (py, mt, nh); i = bid>>3 -> (px, nt-sub).
  // Twin blocks (px=0/1, same nt) are adjacent i on the same XCD -> their
  // interleaved 4B stores merge in that XCD's L2.
  const int bid = blockIdx.x;
  const int g = bid & 7, i = bid >> 3;
  const int py = g >> 2;
  const int mt = (g >> 1) & 1;
  const int nh = g & 1;
  const int px = i & 1;
  const int nt = nh * 16 + (i >> 1);   // 0..31
  const int p  = py * 2 + px;
  const int co0 = mt << 8;
  const int n0  = nt << 8;
  const int b   = n0 >> 10;
  const int rb  = (n0 & 1023) >> 5;    // 0,8,16,24

  const int tid  = threadIdx.x;
  const int lane = tid & 63;
  const int wv   = tid >> 6;           // 0..7
  const int wr   = wv >> 2;            // M half (128 rows)
  const int wc   = wv & 3;             // N quarter (64 cols)

  // ---- staging addressing: thread covers rows {srow, srow+64} of a half,
  // phys 16B slot tid&7, fetching logical k-chunk sl = (tid&7)^(srow&7).
  const int srow = tid >> 3;           // 0..63
  const int sl   = (tid & 7) ^ (srow & 7);
  const int dA   = wv * 1024;          // wave-uniform LDS staging base

  const __hip_bfloat16* wpp = weff + ((size_t)p << 20);
  const __hip_bfloat16* pA0 = wpp + (size_t)(co0 + srow) * 2048 + sl * 8;
  const __hip_bfloat16* pA1 = pA0 + (size_t)128 * 2048;
  const __hip_bfloat16* pB00 = xpad +
      ((size_t)(b * 34 + rb + (srow >> 5) + py) * 34 + (srow & 31) + px) * 512 + sl * 8;
  const __hip_bfloat16* pB01 = xpad +
      ((size_t)(b * 34 + rb + ((64 + srow) >> 5) + py) * 34 + ((64 + srow) & 31) + px) * 512 + sl * 8;
  const __hip_bfloat16* pB10 = xpad +
      ((size_t)(b * 34 + rb + ((128 + srow) >> 5) + py) * 34 + ((128 + srow) & 31) + px) * 512 + sl * 8;
  const __hip_bfloat16* pB11 = xpad +
      ((size_t)(b * 34 + rb + ((192 + srow) >> 5) + py) * 34 + ((192 + srow) & 31) + px) * 512 + sl * 8;

  // ---- fragment ds_read addressing (swizzled): row = mm*16 + (lane&15),
  // logical slot = ks*4 + (lane>>4), phys = logical ^ (lane&7).
  const int aoff0 = (lane & 15) * 128 + (((lane >> 4) ^ (lane & 7)) * 16);
  const int aoff1 = (lane & 15) * 128 + ((((lane >> 4) + 4) ^ (lane & 7)) * 16);
  const char* aS0 = lds + wr * 16384;
  const char* aS1 = aS0 + 32768;
  const char* bS0 = lds + 65536 + (wc >> 1) * 16384 + (wc & 1) * 8192;
  const char* bS1 = bS0 + 32768;

  f32x4 acc[8][4] = {};
  bf16x8 A0[8], A1[8], Bf[4];

  // ---- prologue: stage tiles 0 (slot0) and 1 (slot1); wait tile 0.
  ST_A(0, 0, 0); ST_A(0, 1, 0); ST_B(0, 0, 0); ST_B(0, 1, 0);
  ST_A(1, 0, 1); ST_A(1, 1, 1); ST_B(1, 0, 1); ST_B(1, 1, 1);
  GATE("8"); BAR();

  // ---- 16 iterations x 2 K-tiles = K 2048
  ITER(0, false, true, true, "2", "2");
#pragma unroll 1
  for (int t = 2; t <= 28; t += 2) ITER(t, true, true, true, "2", "2");
  ITER(30, true, false, false, "0", "0");

  // ---- epilogue: D layout row=(lane>>4)*4+j, col=lane&15 (m89)
#pragma unroll
  for (int m = 0; m < 8; ++m) {
    const int coB = co0 + wr * 128 + m * 16 + ((lane >> 4) << 2);
    float bv[4];
#pragma unroll
    for (int j = 0; j < 4; ++j) bv[j] = bias[coB + j];
#pragma unroll
    for (int nn = 0; nn < 4; ++nn) {
      const int nl = wc * 64 + nn * 16 + (lane & 15);
      const int rr = rb + (nl >> 5);
      const int ss = nl & 31;
      const int oh = rr * 2 + py;
      const int ow = ss * 2 + px;
      float* op = out + (((size_t)(b * 512 + coB) << 6) + oh) * 64 + ow;
#pragma unroll
      for (int j = 0; j < 4; ++j)
        op[(size_t)j * 4096] = acc[m][nn][j] + bv[j];
    }
  }
}

// ---------------------------------------------------------------------------
extern "C" void kernel_launch(void* const* d_in, const int* in_sizes, int n_in,
                              void* d_out, int out_size, void* d_ws, size_t ws_size,
                              hipStream_t stream) {
  (void)in_sizes; (void)n_in; (void)out_size; (void)ws_size;
  const float* x  = (const float*)d_in[0];   // [8][512][32][32]
  const float* w  = (const float*)d_in[1];   // [512][512][3][3]
  const float* bs = (const float*)d_in[2];   // [512]
  float* out = (float*)d_out;                // [8][512][64][64]
  char* ws = (char*)d_ws;
  __hip_bfloat16* xpad = (__hip_bfloat16*)ws;                 // 9,467,904 B
  __hip_bfloat16* weff = (__hip_bfloat16*)(ws + (10u << 20)); // 8,388,608 B
  hipMemsetAsync(xpad, 0, (size_t)8 * 34 * 34 * 512 * 2, stream);
  prep_weff<<<dim3(1024), dim3(256), 0, stream>>>(w, weff);
  prep_xpad<<<dim3(2048), dim3(256), 0, stream>>>(x, xpad);
  upconv_gemm<<<dim3(256), dim3(512), 131072, stream>>>(xpad, weff, bs, out);
}

// Round 5
// 89.054 us; speedup vs baseline: 1.1835x; 1.0254x over previous
//
#include <hip/hip_runtime.h>
#include <hip/hip_bf16.h>
#include <stdint.h>

// Upsample2x(nearest) + Conv3x3(pad1) + bias via the parity trick:
//   out[b,co,2r+py,2s+px] = bias[co] +
//     sum_{ky,kx in {0,1}, ci} weff[py,px][co][ky,kx,ci] * xpad[b, r+py+ky, s+px+kx, ci]
// 4 parity GEMMs: M=512(co) x N=8192(b,r,s) x K=2048.
// R5: R4's 8-phase schedule relaxed: NO sched_barrier(0), ONE barrier per
// 2 phases (4/iter). Hazard-audited: every stage-write is >=1 barrier after
// the last read of its region; gates vmcnt(2) at ph3/ph7 before barriers.

typedef __attribute__((ext_vector_type(8)))  __bf16 bf16x8;
typedef __attribute__((ext_vector_type(4)))  float  f32x4;
typedef __attribute__((ext_vector_type(4)))  int    int4v;

__device__ __forceinline__ void async16(const void* g, void* l) {
  __builtin_amdgcn_global_load_lds(
      (const __attribute__((address_space(1))) void*)g,
      (__attribute__((address_space(3))) void*)l,
      16, 0, 0);
}

// ---------------------------------------------------------------------------
__global__ void prep_weff(const float* __restrict__ w,
                          __hip_bfloat16* __restrict__ weff) {
  const int idx = blockIdx.x * 256 + threadIdx.x;   // co*512 + ci
  const int co = idx >> 9;
  const int ci = idx & 511;
  const float* wp = w + (size_t)idx * 9;            // [co][ci][3][3]
  float t[9];
#pragma unroll
  for (int i = 0; i < 9; ++i) t[i] = wp[i];
#pragma unroll
  for (int py = 0; py < 2; ++py) {
#pragma unroll
    for (int px = 0; px < 2; ++px) {
      const int p = py * 2 + px;
#pragma unroll
      for (int ky = 0; ky < 2; ++ky) {
        const int ulo = (ky == 0) ? 0 : (py == 0 ? 1 : 2);
        const int uhi = (ky == 0) ? (py == 0 ? 0 : 1) : 2;
#pragma unroll
        for (int kx = 0; kx < 2; ++kx) {
          const int vlo = (kx == 0) ? 0 : (px == 0 ? 1 : 2);
          const int vhi = (kx == 0) ? (px == 0 ? 0 : 1) : 2;
          float s = 0.f;
          for (int u = ulo; u <= uhi; ++u)
            for (int v = vlo; v <= vhi; ++v)
              s += t[u * 3 + v];
          const int kk = ky * 2 + kx;
          weff[(((size_t)p * 512 + co) * 4 + kk) * 512 + ci] = __float2bfloat16(s);
        }
      }
    }
  }
}

// ---------------------------------------------------------------------------
__global__ void prep_xpad(const float* __restrict__ x,
                          __hip_bfloat16* __restrict__ xpad) {
  const int blk = blockIdx.x;          // 8b * 32r * 8cib = 2048
  const int cib = blk & 7;
  const int r   = (blk >> 3) & 31;
  const int b   = blk >> 8;
  const int tid = threadIdx.x;
  __shared__ __align__(16) __hip_bfloat16 ldsT[32][80];
  const int ci_l = tid >> 2;
  const int wq   = tid & 3;
  const float* xp = x + (((size_t)(b * 512 + cib * 64 + ci_l) * 32 + r) * 32) + wq * 8;
  float4 v0 = *(const float4*)(xp);
  float4 v1 = *(const float4*)(xp + 4);
  const int wb = wq * 8;
  ldsT[wb + 0][ci_l] = __float2bfloat16(v0.x);
  ldsT[wb + 1][ci_l] = __float2bfloat16(v0.y);
  ldsT[wb + 2][ci_l] = __float2bfloat16(v0.z);
  ldsT[wb + 3][ci_l] = __float2bfloat16(v0.w);
  ldsT[wb + 4][ci_l] = __float2bfloat16(v1.x);
  ldsT[wb + 5][ci_l] = __float2bfloat16(v1.y);
  ldsT[wb + 6][ci_l] = __float2bfloat16(v1.z);
  ldsT[wb + 7][ci_l] = __float2bfloat16(v1.w);
  __syncthreads();
  const int w_o = tid >> 3;
  const int ch  = tid & 7;
  char* dst = (char*)xpad +
      ((((size_t)(b * 34 + (r + 1)) * 34) + (w_o + 1)) * 512 + cib * 64 + ch * 8) * 2;
  *(int4v*)dst = *(const int4v*)&ldsT[w_o][ch * 8];
}

// ---------------------------------------------------------------------------
// LDS: A slot d @ d*32768 (half h @ +h*16384), B @ 65536 + d*32768 + h*16384.
// Half layout: [128 rows][8 slots x 16B], phys slot = logical ^ (row&7),
// swizzle applied on global staging source AND ds_read address (rule #21).
#define MM(a, b, c) __builtin_amdgcn_mfma_f32_16x16x32_bf16((a), (b), (c), 0, 0, 0)
#define BAR() asm volatile("s_barrier" ::: "memory")
#define PRIO(x) __builtin_amdgcn_s_setprio(x)
#define GATE(N) asm volatile("s_waitcnt vmcnt(" N ")" ::: "memory")

#define ST_A(T, h, d) do {                                                     \
    char* _l = lds + (d) * 32768 + (h) * 16384 + dA;                           \
    const __hip_bfloat16* _g = ((h) ? pA1 : pA0) + (size_t)(T) * 64;           \
    async16(_g, _l); async16(_g + 131072, _l + 8192); } while (0)

#define OFFB(T) (((((T) >> 4) * 34) + (((T) >> 3) & 1)) * 512 + ((T) & 7) * 64)
#define ST_B(T, h, d) do {                                                     \
    char* _l = lds + 65536 + (d) * 32768 + (h) * 16384 + dA;                   \
    const int _o = OFFB(T);                                                    \
    async16(((h) ? pB10 : pB00) + _o, _l);                                     \
    async16(((h) ? pB11 : pB01) + _o, _l + 8192); } while (0)

#define RD_A(D, S, mb) do {                                                    \
    _Pragma("unroll") for (int _m = 0; _m < 4; ++_m) {                         \
      (D)[_m * 2]     = *(const bf16x8*)((S) + ((mb) + _m) * 2048 + aoff0);    \
      (D)[_m * 2 + 1] = *(const bf16x8*)((S) + ((mb) + _m) * 2048 + aoff1); }  \
  } while (0)

#define RD_B(D, S, nb) do {                                                    \
    _Pragma("unroll") for (int _n = 0; _n < 2; ++_n) {                         \
      (D)[_n * 2]     = *(const bf16x8*)((S) + ((nb) + _n) * 2048 + aoff0);    \
      (D)[_n * 2 + 1] = *(const bf16x8*)((S) + ((nb) + _n) * 2048 + aoff1); }  \
  } while (0)

#define MFMAQ(mb, nb, A, B) do {                                               \
    _Pragma("unroll") for (int _m = 0; _m < 4; ++_m)                           \
      _Pragma("unroll") for (int _n = 0; _n < 2; ++_n) {                       \
        acc[(mb)+_m][(nb)+_n] = MM((A)[_m*2],   (B)[_n*2],   acc[(mb)+_m][(nb)+_n]); \
        acc[(mb)+_m][(nb)+_n] = MM((A)[_m*2+1], (B)[_n*2+1], acc[(mb)+_m][(nb)+_n]); } \
  } while (0)

// One iteration = 2 K-tiles (slot0 = T, slot1 = T+1), 4 super-phases.
// Stage windows: sp0-sp1 finish tile T+1 (slot1); sp1-sp3 tile T+2 (slot0);
// sp3 starts tile T+3 (slot1). Gates: end-sp1 (tile T+1 landed), end-sp3
// (tile T+2 landed). Hazards: each region's stage-write is >=1 barrier
// after its last read (audited in R5 notes above the kernel).
#define ITER(T, SE, SM, S7, G3, G7) do {                                       \
  /* sp0 = ph0+ph1 */                                                          \
  RD_A(A0, aS0, 0); RD_B(Bf, bS0, 0); if (SE) ST_A((T)+1, 1, 1);               \
  PRIO(1); MFMAQ(0, 0, A0, Bf); PRIO(0);                                       \
  RD_A(A1, aS0, 4); if (SE) ST_B((T)+1, 0, 1);                                 \
  PRIO(1); MFMAQ(4, 0, A1, Bf); PRIO(0);                                       \
  BAR();                                                                       \
  /* sp1 = ph2+ph3 */                                                          \
  RD_B(Bf, bS0, 2); if (SE) ST_B((T)+1, 1, 1);                                 \
  PRIO(1); MFMAQ(4, 2, A1, Bf); PRIO(0);                                       \
  if (SM) ST_A((T)+2, 0, 0);                                                   \
  PRIO(1); MFMAQ(0, 2, A0, Bf); PRIO(0);                                       \
  GATE(G3); BAR();                                                             \
  /* sp2 = ph4+ph5 */                                                          \
  RD_A(A0, aS1, 0); RD_B(Bf, bS1, 0); if (SM) ST_A((T)+2, 1, 0);               \
  PRIO(1); MFMAQ(0, 0, A0, Bf); PRIO(0);                                       \
  RD_A(A1, aS1, 4); if (SM) ST_B((T)+2, 0, 0);                                 \
  PRIO(1); MFMAQ(4, 0, A1, Bf); PRIO(0);                                       \
  BAR();                                                                       \
  /* sp3 = ph6+ph7 */                                                          \
  RD_B(Bf, bS1, 2); if (SM) ST_B((T)+2, 1, 0);                                 \
  PRIO(1); MFMAQ(4, 2, A1, Bf); PRIO(0);                                       \
  if (S7) ST_A((T)+3, 0, 1);                                                   \
  PRIO(1); MFMAQ(0, 2, A0, Bf); PRIO(0);                                       \
  GATE(G7); BAR();                                                             \
} while (0)

__global__ __launch_bounds__(512, 2) void upconv_gemm(
    const __hip_bfloat16* __restrict__ xpad,   // [8][34][34][512]
    const __hip_bfloat16* __restrict__ weff,   // [4][512][2048]
    const float* __restrict__ bias,
    float* __restrict__ out) {                 // [8][512][64][64]
  extern __shared__ __align__(16) char lds[]; // 131072 B

  // px-twin XCD map: twin blocks (px=0/1, same nt) adjacent on one XCD.
  const int bid = blockIdx.x;
  const int g = bid & 7, i = bid >> 3;
  const int py = g >> 2;
  const int mt = (g >> 1) & 1;
  const int nh = g & 1;
  const int px = i & 1;
  const int nt = nh * 16 + (i >> 1);   // 0..31
  const int p  = py * 2 + px;
  const int co0 = mt << 8;
  const int n0  = nt << 8;
  const int b   = n0 >> 10;
  const int rb  = (n0 & 1023) >> 5;    // 0,8,16,24

  const int tid  = threadIdx.x;
  const int lane = tid & 63;
  const int wv   = tid >> 6;           // 0..7
  const int wr   = wv >> 2;            // M half (128 rows)
  const int wc   = wv & 3;             // N quarter (64 cols)

  // ---- staging addressing: thread covers rows {srow, srow+64} of a half,
  // phys 16B slot tid&7, fetching logical k-chunk sl = (tid&7)^(srow&7).
  const int srow = tid >> 3;           // 0..63
  const int sl   = (tid & 7) ^ (srow & 7);
  const int dA   = wv * 1024;          // wave-uniform LDS staging base

  const __hip_bfloat16* wpp = weff + ((size_t)p << 20);
  const __hip_bfloat16* pA0 = wpp + (size_t)(co0 + srow) * 2048 + sl * 8;
  const __hip_bfloat16* pA1 = pA0 + (size_t)128 * 2048;
  const __hip_bfloat16* pB00 = xpad +
      ((size_t)(b * 34 + rb + (srow >> 5) + py) * 34 + (srow & 31) + px) * 512 + sl * 8;
  const __hip_bfloat16* pB01 = xpad +
      ((size_t)(b * 34 + rb + ((64 + srow) >> 5) + py) * 34 + ((64 + srow) & 31) + px) * 512 + sl * 8;
  const __hip_bfloat16* pB10 = xpad +
      ((size_t)(b * 34 + rb + ((128 + srow) >> 5) + py) * 34 + ((128 + srow) & 31) + px) * 512 + sl * 8;
  const __hip_bfloat16* pB11 = xpad +
      ((size_t)(b * 34 + rb + ((192 + srow) >> 5) + py) * 34 + ((192 + srow) & 31) + px) * 512 + sl * 8;

  // ---- fragment ds_read addressing (swizzled): row = mm*16 + (lane&15),
  // logical slot = ks*4 + (lane>>4), phys = logical ^ (lane&7).
  const int aoff0 = (lane & 15) * 128 + (((lane >> 4) ^ (lane & 7)) * 16);
  const int aoff1 = (lane & 15) * 128 + ((((lane >> 4) + 4) ^ (lane & 7)) * 16);
  const char* aS0 = lds + wr * 16384;
  const char* aS1 = aS0 + 32768;
  const char* bS0 = lds + 65536 + (wc >> 1) * 16384 + (wc & 1) * 8192;
  const char* bS1 = bS0 + 32768;

  f32x4 acc[8][4] = {};
  bf16x8 A0[8], A1[8], Bf[4];

  // ---- prologue: stage tiles 0 (slot0) and 1 (slot1); wait tile 0.
  ST_A(0, 0, 0); ST_A(0, 1, 0); ST_B(0, 0, 0); ST_B(0, 1, 0);
  ST_A(1, 0, 1); ST_A(1, 1, 1); ST_B(1, 0, 1); ST_B(1, 1, 1);
  GATE("8"); BAR();

  // ---- 16 iterations x 2 K-tiles = K 2048
  ITER(0, false, true, true, "2", "2");
#pragma unroll 1
  for (int t = 2; t <= 28; t += 2) ITER(t, true, true, true, "2", "2");
  ITER(30, true, false, false, "0", "0");

  // ---- epilogue: D layout row=(lane>>4)*4+j, col=lane&15 (m89)
#pragma unroll
  for (int m = 0; m < 8; ++m) {
    const int coB = co0 + wr * 128 + m * 16 + ((lane >> 4) << 2);
    float bv[4];
#pragma unroll
    for (int j = 0; j < 4; ++j) bv[j] = bias[coB + j];
#pragma unroll
    for (int nn = 0; nn < 4; ++nn) {
      const int nl = wc * 64 + nn * 16 + (lane & 15);
      const int rr = rb + (nl >> 5);
      const int ss = nl & 31;
      const int oh = rr * 2 + py;
      const int ow = ss * 2 + px;
      float* op = out + (((size_t)(b * 512 + coB) << 6) + oh) * 64 + ow;
#pragma unroll
      for (int j = 0; j < 4; ++j)
        op[(size_t)j * 4096] = acc[m][nn][j] + bv[j];
    }
  }
}

// ---------------------------------------------------------------------------
extern "C" void kernel_launch(void* const* d_in, const int* in_sizes, int n_in,
                              void* d_out, int out_size, void* d_ws, size_t ws_size,
                              hipStream_t stream) {
  (void)in_sizes; (void)n_in; (void)out_size; (void)ws_size;
  const float* x  = (const float*)d_in[0];   // [8][512][32][32]
  const float* w  = (const float*)d_in[1];   // [512][512][3][3]
  const float* bs = (const float*)d_in[2];   // [512]
  float* out = (float*)d_out;                // [8][512][64][64]
  char* ws = (char*)d_ws;
  __hip_bfloat16* xpad = (__hip_bfloat16*)ws;                 // 9,467,904 B
  __hip_bfloat16* weff = (__hip_bfloat16*)(ws + (10u << 20)); // 8,388,608 B
  hipMemsetAsync(xpad, 0, (size_t)8 * 34 * 34 * 512 * 2, stream);
  prep_weff<<<dim3(1024), dim3(256), 0, stream>>>(w, weff);
  prep_xpad<<<dim3(2048), dim3(256), 0, stream>>>(x, xpad);
  upconv_gemm<<<dim3(256), dim3(512), 131072, stream>>>(xpad, weff, bs, out);
}

// Round 6
// 84.259 us; speedup vs baseline: 1.2508x; 1.0569x over previous
//
#include <hip/hip_runtime.h>
#include <hip/hip_bf16.h>
#include <stdint.h>

// Upsample2x(nearest) + Conv3x3(pad1) + bias via the parity trick:
//   out[b,co,2r+py,2s+px] = bias[co] +
//     sum_{ky,kx in {0,1}, ci} weff[py,px][co][ky,kx,ci] * xpad[b, r+py+ky, s+px+kx, ci]
// 4 parity GEMMs: M=512(co) x N=8192(b,r,s) x K=2048.
// R6: register-pipelined phases. Per K-tile: 4 phases (Q00,Q10,Q11,Q01); each
// phase issues ds_reads for a FUTURE phase (distance >=1) then MFMAs on frags
// read earlier. A-sets ping-pong (Aa/Ab), B-sets fixed (Ba=n0-1, Bb=n2-3).
// 2 barriers + 1 vmcnt(4) gate per K-tile. Staging: ST_A(T+2)@P2, ST_B(T+2)@P3.

typedef __attribute__((ext_vector_type(8)))  __bf16 bf16x8;
typedef __attribute__((ext_vector_type(4)))  float  f32x4;
typedef __attribute__((ext_vector_type(4)))  int    int4v;

__device__ __forceinline__ void async16(const void* g, void* l) {
  __builtin_amdgcn_global_load_lds(
      (const __attribute__((address_space(1))) void*)g,
      (__attribute__((address_space(3))) void*)l,
      16, 0, 0);
}

// ---------------------------------------------------------------------------
__global__ void prep_weff(const float* __restrict__ w,
                          __hip_bfloat16* __restrict__ weff) {
  const int idx = blockIdx.x * 256 + threadIdx.x;   // co*512 + ci
  const int co = idx >> 9;
  const int ci = idx & 511;
  const float* wp = w + (size_t)idx * 9;            // [co][ci][3][3]
  float t[9];
#pragma unroll
  for (int i = 0; i < 9; ++i) t[i] = wp[i];
#pragma unroll
  for (int py = 0; py < 2; ++py) {
#pragma unroll
    for (int px = 0; px < 2; ++px) {
      const int p = py * 2 + px;
#pragma unroll
      for (int ky = 0; ky < 2; ++ky) {
        const int ulo = (ky == 0) ? 0 : (py == 0 ? 1 : 2);
        const int uhi = (ky == 0) ? (py == 0 ? 0 : 1) : 2;
#pragma unroll
        for (int kx = 0; kx < 2; ++kx) {
          const int vlo = (kx == 0) ? 0 : (px == 0 ? 1 : 2);
          const int vhi = (kx == 0) ? (px == 0 ? 0 : 1) : 2;
          float s = 0.f;
          for (int u = ulo; u <= uhi; ++u)
            for (int v = vlo; v <= vhi; ++v)
              s += t[u * 3 + v];
          const int kk = ky * 2 + kx;
          weff[(((size_t)p * 512 + co) * 4 + kk) * 512 + ci] = __float2bfloat16(s);
        }
      }
    }
  }
}

// ---------------------------------------------------------------------------
__global__ void prep_xpad(const float* __restrict__ x,
                          __hip_bfloat16* __restrict__ xpad) {
  const int blk = blockIdx.x;          // 8b * 32r * 8cib = 2048
  const int cib = blk & 7;
  const int r   = (blk >> 3) & 31;
  const int b   = blk >> 8;
  const int tid = threadIdx.x;
  __shared__ __align__(16) __hip_bfloat16 ldsT[32][80];
  const int ci_l = tid >> 2;
  const int wq   = tid & 3;
  const float* xp = x + (((size_t)(b * 512 + cib * 64 + ci_l) * 32 + r) * 32) + wq * 8;
  float4 v0 = *(const float4*)(xp);
  float4 v1 = *(const float4*)(xp + 4);
  const int wb = wq * 8;
  ldsT[wb + 0][ci_l] = __float2bfloat16(v0.x);
  ldsT[wb + 1][ci_l] = __float2bfloat16(v0.y);
  ldsT[wb + 2][ci_l] = __float2bfloat16(v0.z);
  ldsT[wb + 3][ci_l] = __float2bfloat16(v0.w);
  ldsT[wb + 4][ci_l] = __float2bfloat16(v1.x);
  ldsT[wb + 5][ci_l] = __float2bfloat16(v1.y);
  ldsT[wb + 6][ci_l] = __float2bfloat16(v1.z);
  ldsT[wb + 7][ci_l] = __float2bfloat16(v1.w);
  __syncthreads();
  const int w_o = tid >> 3;
  const int ch  = tid & 7;
  char* dst = (char*)xpad +
      ((((size_t)(b * 34 + (r + 1)) * 34) + (w_o + 1)) * 512 + cib * 64 + ch * 8) * 2;
  *(int4v*)dst = *(const int4v*)&ldsT[w_o][ch * 8];
}

// ---------------------------------------------------------------------------
// LDS: A slot d @ d*32768 (half h @ +h*16384), B @ 65536 + d*32768 + h*16384.
// Half layout: [128 rows][8 slots x 16B], phys slot = logical ^ (row&7),
// swizzle on global staging source AND ds_read address (rule #21).
#define MM(a, b, c) __builtin_amdgcn_mfma_f32_16x16x32_bf16((a), (b), (c), 0, 0, 0)
#define BAR() asm volatile("s_barrier" ::: "memory")
#define PRIO(x) __builtin_amdgcn_s_setprio(x)
#define GATE(N) asm volatile("s_waitcnt vmcnt(" N ")" ::: "memory")

#define ST_A(T, d) do {                                                        \
    char* _l = lds + (d) * 32768 + dA;                                         \
    const __hip_bfloat16* _g = pA0 + (size_t)(T) * 64;                         \
    async16(_g, _l); async16(_g + 131072, _l + 8192);                          \
    async16(_g + 262144, _l + 16384); async16(_g + 393216, _l + 24576);        \
  } while (0)

#define OFFB(T) (((((T) >> 4) * 34) + (((T) >> 3) & 1)) * 512 + ((T) & 7) * 64)
#define ST_B(T, d) do {                                                        \
    char* _l = lds + 65536 + (d) * 32768 + dA;                                 \
    const int _o = OFFB(T);                                                    \
    async16(pB00 + _o, _l); async16(pB01 + _o, _l + 8192);                     \
    async16(pB10 + _o, _l + 16384); async16(pB11 + _o, _l + 24576);            \
  } while (0)

#define RD_A(D, S, mb) do {                                                    \
    _Pragma("unroll") for (int _m = 0; _m < 4; ++_m) {                         \
      (D)[_m * 2]     = *(const bf16x8*)((S) + ((mb) + _m) * 2048 + aoff0);    \
      (D)[_m * 2 + 1] = *(const bf16x8*)((S) + ((mb) + _m) * 2048 + aoff1); }  \
  } while (0)

#define RD_B(D, S, nb) do {                                                    \
    _Pragma("unroll") for (int _n = 0; _n < 2; ++_n) {                         \
      (D)[_n * 2]     = *(const bf16x8*)((S) + ((nb) + _n) * 2048 + aoff0);    \
      (D)[_n * 2 + 1] = *(const bf16x8*)((S) + ((nb) + _n) * 2048 + aoff1); }  \
  } while (0)

#define MFMAQ(mb, nb, A, B) do {                                               \
    _Pragma("unroll") for (int _m = 0; _m < 4; ++_m)                           \
      _Pragma("unroll") for (int _n = 0; _n < 2; ++_n) {                       \
        acc[(mb)+_m][(nb)+_n] = MM((A)[_m*2],   (B)[_n*2],   acc[(mb)+_m][(nb)+_n]); \
        acc[(mb)+_m][(nb)+_n] = MM((A)[_m*2+1], (B)[_n*2+1], acc[(mb)+_m][(nb)+_n]); } \
  } while (0)

// One iteration = 2 K-tiles. Even tile T (slot0): A0=Aa, A1=Ab; odd (slot1):
// A0=Ab, A1=Aa. Ba = n0-1 always, Bb = n2-3 always.
// Per tile: P0{rd A1 | Q00} P1{rd B1 | Q10 | BAR}
//           P2{ST_A(T+2) | Q11 | GATE | BAR} P3{rd next A0,B0 | ST_B(T+2) | Q01}
#define ITER(T, SE, SO, GE, GO, LAST) do {                                     \
  /* even tile: slot0 */                                                       \
  RD_A(Ab, aS0, 4);                                                            \
  PRIO(1); MFMAQ(0, 0, Aa, Ba); PRIO(0);                                       \
  RD_B(Bb, bS0, 2);                                                            \
  PRIO(1); MFMAQ(4, 0, Ab, Ba); PRIO(0);                                       \
  BAR();                                                                       \
  if (SE) ST_A((T) + 2, 0);                                                    \
  PRIO(1); MFMAQ(4, 2, Ab, Bb); PRIO(0);                                       \
  GATE(GE); BAR();                                                             \
  RD_A(Ab, aS1, 0); RD_B(Ba, bS1, 0);                                          \
  if (SE) ST_B((T) + 2, 0);                                                    \
  PRIO(1); MFMAQ(0, 2, Aa, Bb); PRIO(0);                                       \
  /* odd tile: slot1 */                                                        \
  RD_A(Aa, aS1, 4);                                                            \
  PRIO(1); MFMAQ(0, 0, Ab, Ba); PRIO(0);                                       \
  RD_B(Bb, bS1, 2);                                                            \
  PRIO(1); MFMAQ(4, 0, Aa, Ba); PRIO(0);                                       \
  BAR();                                                                       \
  if (SO) ST_A((T) + 3, 1);                                                    \
  PRIO(1); MFMAQ(4, 2, Aa, Bb); PRIO(0);                                       \
  GATE(GO); BAR();                                                             \
  if (!LAST) { RD_A(Aa, aS0, 0); RD_B(Ba, bS0, 0); }                           \
  if (SO) ST_B((T) + 3, 1);                                                    \
  PRIO(1); MFMAQ(0, 2, Ab, Bb); PRIO(0);                                       \
} while (0)

__global__ __launch_bounds__(512, 2) void upconv_gemm(
    const __hip_bfloat16* __restrict__ xpad,   // [8][34][34][512]
    const __hip_bfloat16* __restrict__ weff,   // [4][512][2048]
    const float* __restrict__ bias,
    float* __restrict__ out) {                 // [8][512][64][64]
  extern __shared__ __align__(16) char lds[]; // 131072 B

  // px-twin XCD map: twin blocks (px=0/1, same nt) adjacent on one XCD.
  const int bid = blockIdx.x;
  const int g = bid & 7, i = bid >> 3;
  const int py = g >> 2;
  const int mt = (g >> 1) & 1;
  const int nh = g & 1;
  const int px = i & 1;
  const int nt = nh * 16 + (i >> 1);   // 0..31
  const int p  = py * 2 + px;
  const int co0 = mt << 8;
  const int n0  = nt << 8;
  const int b   = n0 >> 10;
  const int rb  = (n0 & 1023) >> 5;    // 0,8,16,24

  const int tid  = threadIdx.x;
  const int lane = tid & 63;
  const int wv   = tid >> 6;           // 0..7
  const int wr   = wv >> 2;            // M half (128 rows)
  const int wc   = wv & 3;             // N quarter (64 cols)

  // ---- staging addressing: thread covers row srow of each 128-row half,
  // phys 16B slot tid&7, fetching logical k-chunk sl = (tid&7)^(srow&7).
  // ST_A/ST_B stage BOTH halves (4 async16 each).
  const int srow = tid >> 3;           // 0..63
  const int sl   = (tid & 7) ^ (srow & 7);
  const int dA   = wv * 1024;          // wave-uniform LDS staging base

  const __hip_bfloat16* wpp = weff + ((size_t)p << 20);
  const __hip_bfloat16* pA0 = wpp + (size_t)(co0 + srow) * 2048 + sl * 8;
  const __hip_bfloat16* pB00 = xpad +
      ((size_t)(b * 34 + rb + (srow >> 5) + py) * 34 + (srow & 31) + px) * 512 + sl * 8;
  // rows 64/128/192 + srow: (64k+srow)&31 == srow&31, (64k+srow)>>5 == (srow>>5)+2k
  const __hip_bfloat16* pB01 = pB00 + (size_t)2 * 34 * 512;
  const __hip_bfloat16* pB10 = pB00 + (size_t)4 * 34 * 512;
  const __hip_bfloat16* pB11 = pB00 + (size_t)6 * 34 * 512;

  // ---- fragment ds_read addressing (swizzled): row = mm*16 + (lane&15),
  // logical slot = ks*4 + (lane>>4), phys = logical ^ (lane&7).
  const int aoff0 = (lane & 15) * 128 + (((lane >> 4) ^ (lane & 7)) * 16);
  const int aoff1 = (lane & 15) * 128 + ((((lane >> 4) + 4) ^ (lane & 7)) * 16);
  const char* aS0 = lds + wr * 16384;
  const char* aS1 = aS0 + 32768;
  const char* bS0 = lds + 65536 + (wc >> 1) * 16384 + (wc & 1) * 8192;
  const char* bS1 = bS0 + 32768;

  f32x4 acc[8][4] = {};
  bf16x8 Aa[8], Ab[8], Ba[4], Bb[4];

  // ---- prologue: stage tiles 0 (slot0) and 1 (slot1); wait tile 0;
  // pre-read tile0's A0 (m0-3) and B0 (n0-1).
  ST_A(0, 0); ST_B(0, 0);
  ST_A(1, 1); ST_B(1, 1);
  GATE("8"); BAR();
  RD_A(Aa, aS0, 0); RD_B(Ba, bS0, 0);

  // ---- 16 iterations x 2 K-tiles = K 2048
#pragma unroll 1
  for (int t = 0; t <= 28; t += 2) ITER(t, true, true, "4", "4", false);
  ITER(30, false, false, "0", "0", true);

  // ---- epilogue: D layout row=(lane>>4)*4+j, col=lane&15 (m89)
#pragma unroll
  for (int m = 0; m < 8; ++m) {
    const int coB = co0 + wr * 128 + m * 16 + ((lane >> 4) << 2);
    float bv[4];
#pragma unroll
    for (int j = 0; j < 4; ++j) bv[j] = bias[coB + j];
#pragma unroll
    for (int nn = 0; nn < 4; ++nn) {
      const int nl = wc * 64 + nn * 16 + (lane & 15);
      const int rr = rb + (nl >> 5);
      const int ss = nl & 31;
      const int oh = rr * 2 + py;
      const int ow = ss * 2 + px;
      float* op = out + (((size_t)(b * 512 + coB) << 6) + oh) * 64 + ow;
#pragma unroll
      for (int j = 0; j < 4; ++j)
        op[(size_t)j * 4096] = acc[m][nn][j] + bv[j];
    }
  }
}

// ---------------------------------------------------------------------------
extern "C" void kernel_launch(void* const* d_in, const int* in_sizes, int n_in,
                              void* d_out, int out_size, void* d_ws, size_t ws_size,
                              hipStream_t stream) {
  (void)in_sizes; (void)n_in; (void)out_size; (void)ws_size;
  const float* x  = (const float*)d_in[0];   // [8][512][32][32]
  const float* w  = (const float*)d_in[1];   // [512][512][3][3]
  const float* bs = (const float*)d_in[2];   // [512]
  float* out = (float*)d_out;                // [8][512][64][64]
  char* ws = (char*)d_ws;
  __hip_bfloat16* xpad = (__hip_bfloat16*)ws;                 // 9,467,904 B
  __hip_bfloat16* weff = (__hip_bfloat16*)(ws + (10u << 20)); // 8,388,608 B
  hipMemsetAsync(xpad, 0, (size_t)8 * 34 * 34 * 512 * 2, stream);
  prep_weff<<<dim3(1024), dim3(256), 0, stream>>>(w, weff);
  prep_xpad<<<dim3(2048), dim3(256), 0, stream>>>(x, xpad);
  upconv_gemm<<<dim3(256), dim3(512), 131072, stream>>>(xpad, weff, bs, out);
}